// Round 5
// baseline (401.076 us; speedup 1.0000x reference)
//
#include <hip/hip_runtime.h>
#include <stdint.h>

// out = x @ tanh(block_diag(blocks)) -- 16 blocks of 256x256. ALL BUFFERS FLOAT32.
// tanh_pack: diagonal blocks -> bf16 wsT[j][n][k] (2 MB in d_ws).
// bdgemm_red: K-split-across-waves GEMM. Wave w owns K-slice [w*64,(w+1)*64):
//   B frags = 32 VGPRs/wave. A prefetched 1 step ahead (4 float4/lane in flight).
//   Partials reduced via 20 KB LDS bounce; raw s_barrier (asm, memory clobber,
//   lgkm-only waits) so global prefetch/stores stay in flight across barriers.

typedef float floatx4 __attribute__((ext_vector_type(4)));
typedef __bf16 bf16x8 __attribute__((ext_vector_type(8)));

#define LDX 4096
#define NBLK 16
#define BS 256
#define MSTEPS 16  // 16-row steps per WG -> WG covers 256 rows
#define CS 20      // LDS reduce buffer: col stride (16 rows + 4 pad), 16B aligned

__device__ __forceinline__ unsigned int f2bf(float f) {
  union { float f; unsigned int i; } x;
  x.f = f;
  unsigned int r = x.i + 0x7FFFu + ((x.i >> 16) & 1u);  // RNE
  return r >> 16;
}

__device__ __forceinline__ bf16x8 cvt8(float4 a, float4 b) {
  union { unsigned int u[4]; bf16x8 v; } r;
  r.u[0] = f2bf(a.x) | (f2bf(a.y) << 16);
  r.u[1] = f2bf(a.z) | (f2bf(a.w) << 16);
  r.u[2] = f2bf(b.x) | (f2bf(b.y) << 16);
  r.u[3] = f2bf(b.z) | (f2bf(b.w) << 16);
  return r.v;
}

// Raw workgroup barrier: LDS ordering only. No vmcnt drain -> global loads/stores
// issued before it remain in flight. "memory" clobber pins compiler ordering.
__device__ __forceinline__ void lds_barrier() {
  asm volatile("s_waitcnt lgkmcnt(0)\n\ts_barrier" ::: "memory");
}

// wsT[j*65536 + n*256 + k] = tanh(blocks[(j*256+k)*4096 + j*256 + n]), stored bf16.
__global__ __launch_bounds__(256) void tanh_pack(const float* __restrict__ blocks,
                                                 unsigned short* __restrict__ wsT) {
  __shared__ float tile[64][65];
  const int t = threadIdx.x;
  const int tc = blockIdx.x, tr = blockIdx.y, j = blockIdx.z;
  const float* src = blocks + (size_t)(j * BS + tr * 64) * LDX + j * BS + tc * 64;
#pragma unroll
  for (int it = 0; it < 8; ++it) {
    int v = it * 256 + t;
    int row = v >> 5;
    int c2 = (v & 31) * 2;
    float2 f = *(const float2*)(src + (size_t)row * LDX + c2);
    tile[row][c2] = tanhf(f.x);
    tile[row][c2 + 1] = tanhf(f.y);
  }
  __syncthreads();
  unsigned short* dst = wsT + (size_t)j * BS * BS + (size_t)(tc * 64) * BS + tr * 64;
#pragma unroll
  for (int it = 0; it < 8; ++it) {
    int v = it * 256 + t;
    int nn = v >> 5;
    int k2 = (v & 31) * 2;
    unsigned int pair = f2bf(tile[k2][nn]) | (f2bf(tile[k2 + 1][nn]) << 16);
    *(unsigned int*)(dst + (size_t)nn * BS + k2) = pair;
  }
}

// grid = (nslab 4, mslab 32, j 16). WG covers 256 rows x 64 n-cols of block j.
// Wave w computes the K-slice partial; LDS reduce; distributed store.
__global__ __launch_bounds__(256, 4) void bdgemm_red(const float* __restrict__ x,
                                                     const unsigned short* __restrict__ wsT,
                                                     float* __restrict__ out) {
  __shared__ float red[4 * 64 * CS];  // [w][c 64][r CS], 20 KB
  const int t = threadIdx.x;
  const int lane = t & 63;
  const int w = t >> 6;       // wave = K-slice owner
  const int fr = lane & 15;   // MFMA m/n index
  const int q = lane >> 4;    // MFMA k-subgroup (frag k-off = q*8), C-row base = q*4
  const int nslab = blockIdx.x;  // 0..3
  const int mslab = blockIdx.y;  // 0..31
  const int j = blockIdx.z;      // 0..15
  const int n0 = nslab * 64;
  const int rowbase = mslab * (MSTEPS * 16);

  // ---- B fragments: Bf[kq][nf], 32 VGPRs. B[k][n] with k in wave's 64-slice ----
  const unsigned short* wb = wsT + (size_t)j * (BS * BS);
  bf16x8 Bf[2][4];
#pragma unroll
  for (int kq = 0; kq < 2; ++kq)
#pragma unroll
    for (int nf = 0; nf < 4; ++nf)
      Bf[kq][nf] =
          *(const bf16x8*)(wb + (size_t)(n0 + nf * 16 + fr) * BS + w * 64 + kq * 32 + q * 8);

  // A: lane reads row (rowbase + s*16 + fr), k = w*64 + kq*32 + q*8 .. +7
  const float* ax = x + (size_t)(rowbase + fr) * LDX + j * BS + w * 64 + q * 8;

  float4 A[2][4];  // [parity][kq*2+h]
#pragma unroll
  for (int kq = 0; kq < 2; ++kq) {
    A[0][kq * 2] = *(const float4*)(ax + kq * 32);
    A[0][kq * 2 + 1] = *(const float4*)(ax + kq * 32 + 4);
  }

  const int c = t & 63;    // reduce/store: column within n-slab
  const int rq = t >> 6;   // reduce/store: row quad (rows rq*4..rq*4+3)
  float* outb = out + (size_t)(rowbase + rq * 4) * LDX + j * BS + n0 + c;

#pragma unroll
  for (int s = 0; s < MSTEPS; ++s) {
    const int p = s & 1;
    // prefetch next step's A (stays in flight across barriers below)
    if (s + 1 < MSTEPS) {
      const float* an = ax + (size_t)(s + 1) * 16 * LDX;
#pragma unroll
      for (int kq = 0; kq < 2; ++kq) {
        A[p ^ 1][kq * 2] = *(const float4*)(an + kq * 32);
        A[p ^ 1][kq * 2 + 1] = *(const float4*)(an + kq * 32 + 4);
      }
    }

    // partial product for this wave's K-slice
    floatx4 acc[4];
#pragma unroll
    for (int nf = 0; nf < 4; ++nf) acc[nf] = (floatx4){0.f, 0.f, 0.f, 0.f};
#pragma unroll
    for (int kq = 0; kq < 2; ++kq) {
      bf16x8 av = cvt8(A[p][kq * 2], A[p][kq * 2 + 1]);
#pragma unroll
      for (int nf = 0; nf < 4; ++nf)
        acc[nf] = __builtin_amdgcn_mfma_f32_16x16x32_bf16(av, Bf[kq][nf], acc[nf], 0, 0, 0);
    }

    // write partial to LDS: red[(w*64 + nf*16+fr)*CS + q*4 .. +3]  (C/D: col=fr, row=q*4+reg)
#pragma unroll
    for (int nf = 0; nf < 4; ++nf)
      *(floatx4*)(&red[(w * 64 + nf * 16 + fr) * CS + q * 4]) = acc[nf];

    lds_barrier();  // partials visible; prefetch loads still in flight

    // reduce across 4 K-slices and store: thread -> (col c, rows rq*4..+3)
    floatx4 sum = *(const floatx4*)(&red[(0 * 64 + c) * CS + rq * 4]);
#pragma unroll
    for (int w2 = 1; w2 < 4; ++w2)
      sum += *(const floatx4*)(&red[(w2 * 64 + c) * CS + rq * 4]);

    float* op = outb + (size_t)s * 16 * LDX;
#pragma unroll
    for (int i = 0; i < 4; ++i) op[(size_t)i * LDX] = sum[i];

    lds_barrier();  // all reduce-reads done before next step's partial writes
  }
}

// Fallback (ws too small): one-kernel fused path, tanh applied during B staging.
__global__ __launch_bounds__(256) void bdgemm_fused(const float* __restrict__ x,
                                                    const float* __restrict__ blocks,
                                                    float* __restrict__ out) {
  __shared__ unsigned short As[64 * 32];
  __shared__ unsigned short Bs[256 * 40];
  const int t = threadIdx.x;
  const int lane = t & 63;
  const int wave = t >> 6;
  const int mtile = blockIdx.x;
  const int j = blockIdx.y;
  const int m0 = mtile * 64;
  const float* xg = x + (size_t)m0 * LDX + j * BS;
  const int srow = t >> 2;
  const int scol = (t & 3) * 8;
  const int wn = wave * 64;
  const int fr = lane & 15;
  const int fq = (lane >> 4) * 8;

  floatx4 acc[4][4];
#pragma unroll
  for (int a = 0; a < 4; ++a)
#pragma unroll
    for (int b = 0; b < 4; ++b) acc[a][b] = (floatx4){0.f, 0.f, 0.f, 0.f};

  for (int kt = 0; kt < 8; ++kt) {
    const int k0 = kt * 32;
    const float* ap = xg + (size_t)srow * LDX + k0 + scol;
    float4 a0 = *(const float4*)(ap);
    float4 a1 = *(const float4*)(ap + 4);
    uint4 pk;
    pk.x = f2bf(a0.x) | (f2bf(a0.y) << 16);
    pk.y = f2bf(a0.z) | (f2bf(a0.w) << 16);
    pk.z = f2bf(a1.x) | (f2bf(a1.y) << 16);
    pk.w = f2bf(a1.z) | (f2bf(a1.w) << 16);
    *(uint4*)(As + t * 8) = pk;
#pragma unroll
    for (int i = 0; i < 32; ++i) {
      const int idx = i * 256 + t;
      const int kk = idx >> 8;
      const int nn = idx & 255;
      float v = tanhf(blocks[(size_t)(j * BS + k0 + kk) * LDX + j * BS + nn]);
      Bs[nn * 40 + kk] = (unsigned short)f2bf(v);
    }
    __syncthreads();
    bf16x8 af[4], bfm[4];
#pragma unroll
    for (int i = 0; i < 4; ++i) {
      af[i] = *(const bf16x8*)(As + (i * 16 + fr) * 32 + fq);
      bfm[i] = *(const bf16x8*)(Bs + (wn + i * 16 + fr) * 40 + fq);
    }
#pragma unroll
    for (int mi = 0; mi < 4; ++mi)
#pragma unroll
      for (int ni = 0; ni < 4; ++ni)
        acc[mi][ni] =
            __builtin_amdgcn_mfma_f32_16x16x32_bf16(af[mi], bfm[ni], acc[mi][ni], 0, 0, 0);
    __syncthreads();
  }
  const int r0 = (lane >> 4) * 4;
  const int ocol = j * BS + wn + fr;
#pragma unroll
  for (int mi = 0; mi < 4; ++mi)
#pragma unroll
    for (int ni = 0; ni < 4; ++ni) {
      float* op = out + (size_t)(m0 + mi * 16 + r0) * LDX + ocol + ni * 16;
#pragma unroll
      for (int r = 0; r < 4; ++r) op[(size_t)r * LDX] = acc[mi][ni][r];
    }
}

extern "C" void kernel_launch(void* const* d_in, const int* in_sizes, int n_in,
                              void* d_out, int out_size, void* d_ws, size_t ws_size,
                              hipStream_t stream) {
  const float* x = (const float*)d_in[0];       // 8192x4096 f32
  const float* blocks = (const float*)d_in[1];  // 4096x4096 f32
  // d_in[2] (mask) unused: block structure static, tanh(0)=0.
  float* out = (float*)d_out;

  const size_t need = (size_t)NBLK * BS * BS * sizeof(unsigned short);  // 2 MB
  if (d_ws != nullptr && ws_size >= need) {
    unsigned short* wsT = (unsigned short*)d_ws;
    tanh_pack<<<dim3(4, 4, NBLK), 256, 0, stream>>>(blocks, wsT);
    bdgemm_red<<<dim3(4, 32, NBLK), 256, 0, stream>>>(x, wsT, out);
  } else {
    bdgemm_fused<<<dim3(128, NBLK), 256, 0, stream>>>(x, blocks, out);
  }
}